// Round 12
// baseline (107.503 us; speedup 1.0000x reference)
//
#include <hip/hip_runtime.h>
#include <hip/hip_cooperative_groups.h>
#include <math.h>

namespace cg = cooperative_groups;

#define EPSF 1e-7f
#define MAXNF (1.0f - 1e-5f)

typedef __attribute__((ext_vector_type(8))) short short8;
typedef __attribute__((ext_vector_type(4))) float f32x4;

union Pun8 { unsigned short u[8]; short8 s; };

static __device__ __forceinline__ unsigned short f2bf_rn(float f) {
  union { float f; unsigned u; } v;
  v.f = f;
  unsigned r = v.u + 0x7fff + ((v.u >> 16) & 1);  // RNE; inputs are finite
  return (unsigned short)(r >> 16);
}
static __device__ __forceinline__ float bf2f(unsigned short h) {
  union { unsigned u; float f; } v;
  v.u = ((unsigned)h) << 16;
  return v.f;
}

// DPP-based reductions (VALU pipe).
template <int CTRL>
static __device__ __forceinline__ float dpp_add(float v) {
  int s = __builtin_amdgcn_update_dpp(0, __float_as_int(v), CTRL, 0xf, 0xf,
                                      true);
  return v + __int_as_float(s);
}
static __device__ __forceinline__ float wsum(float v) {
  v = dpp_add<0x111>(v);  // row_shr:1
  v = dpp_add<0x112>(v);  // row_shr:2
  v = dpp_add<0x114>(v);  // row_shr:4
  v = dpp_add<0x118>(v);  // row_shr:8
  v = dpp_add<0x142>(v);  // row_bcast:15
  v = dpp_add<0x143>(v);  // row_bcast:31
  return __int_as_float(__builtin_amdgcn_readlane(__float_as_int(v), 63));
}
// Per-16-lane-group sum; FULL sum valid only in lane (lane&15)==15.
static __device__ __forceinline__ float hsum16_t(float v) {
  v = dpp_add<0x111>(v);
  v = dpp_add<0x112>(v);
  v = dpp_add<0x114>(v);
  v = dpp_add<0x118>(v);
  return v;
}

__device__ __forceinline__ float dot4(const float4 a, const float4 b) {
  return a.x * b.x + a.y * b.y + a.z * b.z + a.w * b.w;
}
__device__ __forceinline__ float4 mobius_step(const float4 x, const float4 y) {
  float px = wsum(dot4(x, x));
  float py = wsum(dot4(y, y));
  float pxy = wsum(dot4(x, y));
  float cx = 1.f + 2.f * pxy + py;
  float cy = 1.f - px;
  float inv = 1.f / fmaxf(1.f + 2.f * pxy + px * py, EPSF);
  float4 r;
  r.x = (cx * x.x + cy * y.x) * inv;
  r.y = (cx * x.y + cy * y.y) * inv;
  r.z = (cx * x.z + cy * y.z) * inv;
  r.w = (cx * x.w + cy * y.w) * inv;
  return r;
}

// One cooperative kernel, 256 blocks x 512 threads (1 block/CU).
// Phase 0: pack W1 slice (hidden behind A staging). grid.sync.
// Phase 1: bf16x3 MFMA GEMM + mobius epilogue -> h1. grid.sync.
// Phase 2: blocks 0..63 run layer-2 + classifier -> out.
__global__ __launch_bounds__(512, 2) void
fused_all(const float* __restrict__ features, const float* __restrict__ W1,
          unsigned short* __restrict__ whi, unsigned short* __restrict__ wlo,
          const float* __restrict__ b1, const int* __restrict__ src_idx,
          const int* __restrict__ to_fetch, float* __restrict__ h1,
          const float* __restrict__ W2, const float* __restrict__ b2,
          const float* __restrict__ Wl, const float* __restrict__ bl,
          float* __restrict__ out) {
  const int b4 = blockIdx.x << 2;  // first pair index of this block
  const int tid = threadIdx.x;
  const int w = tid >> 6;          // 0..7
  const int lane = tid & 63;
  const int g = lane >> 4;
  const int r16 = lane & 15;

  __shared__ __align__(16) unsigned short aH[64 * 512];  // 64 KB
  __shared__ __align__(16) unsigned short aL[64 * 512];  // 64 KB
  __shared__ float s_msp[8][64];
  __shared__ float s_fs2[64], s_srow[64];
  __shared__ int s_anode[4];
  __shared__ int s_vn[64];

  // ---- Phase 0: pack one 512-element slice of W1 into MFMA B-frag order.
  // element e -> (id = e>>3, jj = e&7); id = (s,t,l); stored at id*8+jj.
  {
    const int e = (blockIdx.x << 9) | tid;  // 0..131071
    const int id = e >> 3, jj = e & 7;
    const int s = id >> 10, t = (id >> 6) & 15, l = id & 63;
    const int n = t * 16 + (l & 15);
    const int kr = s * 32 + ((l >> 4) << 3) + jj;
    const float wv = W1[kr * 256 + n];
    const unsigned short hb = f2bf_rn(wv);
    whi[id * 8 + jj] = hb;
    wlo[id * 8 + jj] = f2bf_rn(wv - bf2f(hb));
  }

  // ---- Phase 1 staging (independent of pack): gather 64 rows -> LDS bf16.
  if (tid < 4) {
    const int pair = b4 + tid;
    const int jj = pair >> 4, kk = pair & 15;
    s_anode[tid] = src_idx[(to_fetch[jj] + (jj << 10)) * 16 + kk];
  }
  __syncthreads();
  if (tid < 64) s_vn[tid] = src_idx[s_anode[tid >> 4] * 16 + (tid & 15)];
  __syncthreads();

#pragma unroll
  for (int batch = 0; batch < 2; ++batch) {
    float4 f0[4], f1[4];
    const int rb = (w << 3) + (batch << 2);
#pragma unroll
    for (int i = 0; i < 4; ++i) {
      const float* rp = features + (size_t)s_vn[rb + i] * 512 + lane * 8;
      f0[i] = *reinterpret_cast<const float4*>(rp);
      f1[i] = *reinterpret_cast<const float4*>(rp + 4);
    }
#pragma unroll
    for (int i = 0; i < 4; ++i) {
      const int r = rb + i;
      const float fv[8] = {f0[i].x, f0[i].y, f0[i].z, f0[i].w,
                           f1[i].x, f1[i].y, f1[i].z, f1[i].w};
      Pun8 ph, pl;
      float ss = 0.f;
#pragma unroll
      for (int q = 0; q < 8; ++q) {
        ss = fmaf(fv[q], fv[q], ss);
        unsigned short hb = f2bf_rn(fv[q]);
        ph.u[q] = hb;
        pl.u[q] = f2bf_rn(fv[q] - bf2f(hb));
      }
      const int off = r * 512 + ((lane * 8) ^ ((r & 7) * 8));
      *reinterpret_cast<short8*>(&aH[off]) = ph.s;
      *reinterpret_cast<short8*>(&aL[off]) = pl.s;
      ss = wsum(ss);
      if (lane == 0) s_fs2[r] = ss;
    }
  }
  __syncthreads();

  // Pack must be globally visible before B loads.
  cg::this_grid().sync();

  const int g8 = g * 8;
  const int sw = (r16 & 7) * 8;
  const int tbase = w * 2;  // wave's first n-tile
  const short8* Bh = reinterpret_cast<const short8*>(whi);
  const short8* Bl = reinterpret_cast<const short8*>(wlo);

  f32x4 acc[4][2];  // [pair][ntile]
#pragma unroll
  for (int p = 0; p < 4; ++p)
#pragma unroll
    for (int i = 0; i < 2; ++i) acc[p][i] = (f32x4){0.f, 0.f, 0.f, 0.f};

  short8 A0[4][2], A1[4][2];  // [pair][hi/lo]
  short8 B0[2][2], B1[2][2];  // [ntile][hi/lo]

#define LOADA(AR, S)                                                          \
  {                                                                           \
    const int s_ = (S)&15;                                                    \
    _Pragma("unroll") for (int p_ = 0; p_ < 4; ++p_) {                        \
      const int o_ = ((p_ << 4) + r16) * 512 + (((s_ << 5) + g8) ^ sw);       \
      AR[p_][0] = *reinterpret_cast<const short8*>(&aH[o_]);                  \
      AR[p_][1] = *reinterpret_cast<const short8*>(&aL[o_]);                  \
    }                                                                         \
  }
#define LOADB(BR, S)                                                          \
  {                                                                           \
    const int s_ = (S)&15;                                                    \
    _Pragma("unroll") for (int i_ = 0; i_ < 2; ++i_) {                        \
      const int idx_ = ((s_ << 4) + tbase + i_) * 64 + lane;                  \
      BR[i_][0] = Bh[idx_];                                                   \
      BR[i_][1] = Bl[idx_];                                                   \
    }                                                                         \
  }
#define MFMAALL(AR, BR)                                                       \
  _Pragma("unroll") for (int p_ = 0; p_ < 4; ++p_)                            \
      _Pragma("unroll") for (int i_ = 0; i_ < 2; ++i_) acc[p_][i_] =          \
      __builtin_amdgcn_mfma_f32_16x16x32_bf16(AR[p_][0], BR[i_][0],           \
                                              acc[p_][i_], 0, 0, 0);          \
  _Pragma("unroll") for (int p_ = 0; p_ < 4; ++p_)                            \
      _Pragma("unroll") for (int i_ = 0; i_ < 2; ++i_) acc[p_][i_] =          \
      __builtin_amdgcn_mfma_f32_16x16x32_bf16(AR[p_][0], BR[i_][1],           \
                                              acc[p_][i_], 0, 0, 0);          \
  _Pragma("unroll") for (int p_ = 0; p_ < 4; ++p_)                            \
      _Pragma("unroll") for (int i_ = 0; i_ < 2; ++i_) acc[p_][i_] =          \
      __builtin_amdgcn_mfma_f32_16x16x32_bf16(AR[p_][1], BR[i_][0],           \
                                              acc[p_][i_], 0, 0, 0);

  LOADA(A0, 0)
  LOADB(B0, 0)
#pragma unroll 1
  for (int s = 0; s < 16; s += 2) {
    LOADB(B1, s + 1)
    LOADA(A1, s + 1)
    MFMAALL(A0, B0)
    LOADB(B0, s + 2)
    LOADA(A0, s + 2)
    MFMAALL(A1, B1)
  }

  // Row norms of mx: per-lane partial over 2 n-tiles, DPP 16-group reduce
  // (sum valid in lane r16==15), cross-wave sum in LDS.
#pragma unroll
  for (int p = 0; p < 4; ++p) {
    float rs[4];
#pragma unroll
    for (int reg = 0; reg < 4; ++reg) {
      float v = fmaf(acc[p][0][reg], acc[p][0][reg],
                     acc[p][1][reg] * acc[p][1][reg]);
      rs[reg] = hsum16_t(v);
    }
    if (r16 == 15) {
#pragma unroll
      for (int reg = 0; reg < 4; ++reg)
        s_msp[w][(p << 4) + (g << 2) + reg] = rs[reg];
    }
  }
  __syncthreads();
  if (tid < 64) {
    float ms2 = 0.f;
#pragma unroll
    for (int ww = 0; ww < 8; ++ww) ms2 += s_msp[ww][tid];
    const float xn = fminf(fmaxf(0.25f * sqrtf(s_fs2[tid]), EPSF), MAXNF);
    const float mxn = fmaxf(0.25f * sqrtf(ms2), EPSF);
    s_srow[tid] = tanhf(mxn / xn * atanhf(xn)) * 0.25f / mxn;
  }
  __syncthreads();

  // Scaled transformed rows overlay the (now dead) aH plane: 64x256 f32.
  float(*trow)[256] = reinterpret_cast<float(*)[256]>(&aH[0]);
#pragma unroll
  for (int p = 0; p < 4; ++p) {
#pragma unroll
    for (int i = 0; i < 2; ++i) {
      const int n = ((tbase + i) << 4) + r16;
#pragma unroll
      for (int reg = 0; reg < 4; ++reg) {
        const int row = (p << 4) + (g << 2) + reg;
        trow[row][n] = acc[p][i][reg] * s_srow[row];
      }
    }
  }
  __syncthreads();

  // Chained mobius_add: waves 0..3 each process one pair.
  if (w < 4) {
    const int l4 = lane << 2;
    float4 x = *reinterpret_cast<const float4*>(&trow[w * 16][l4]);
#pragma unroll 1
    for (int kk = 1; kk < 16; ++kk) {
      const float4 y = *reinterpret_cast<const float4*>(&trow[w * 16 + kk][l4]);
      x = mobius_step(x, y);
    }
    x.x *= 0.25f; x.y *= 0.25f; x.z *= 0.25f; x.w *= 0.25f;
    {
      const float4 b = *reinterpret_cast<const float4*>(b1 + l4);
      x = mobius_step(x, b);
    }
    float pn = wsum(dot4(x, x));
    float yn = fminf(fmaxf(sqrtf(pn), EPSF), MAXNF);
    float s = atanhf(yn) / yn;
    float4 v;
    v.x = fmaxf(s * x.x, 0.f);
    v.y = fmaxf(s * x.y, 0.f);
    v.z = fmaxf(s * x.z, 0.f);
    v.w = fmaxf(s * x.w, 0.f);
    float pv = wsum(dot4(v, v));
    float vn = fmaxf(sqrtf(pv), EPSF);
    float s2 = tanhf(vn) / vn;
    float4 h;
    h.x = s2 * v.x;
    h.y = s2 * v.y;
    h.z = s2 * v.z;
    h.w = s2 * v.w;
    *reinterpret_cast<float4*>(h1 + (size_t)(b4 + w) * 256 + l4) = h;
  }
#undef LOADA
#undef LOADB
#undef MFMAALL

  // h1 must be globally visible before phase 2.
  cg::this_grid().sync();

  // ---- Phase 2: blocks 0..63, one output row each (512 threads).
  if (blockIdx.x < 64) {
    const int j = blockIdx.x;
    const int l4 = lane << 2;
    float(*hrows)[256] = reinterpret_cast<float(*)[256]>(&aH[0]);   // 16 KB
    float* xs = reinterpret_cast<float*>(&aH[0]) + 16 * 256;        // 1 KB
    float(*pp)[256] =
        reinterpret_cast<float(*)[256]>(reinterpret_cast<float*>(&aH[0]) +
                                        16 * 256 + 256);            // 8 KB

    __syncthreads();  // ensure phase-1 LDS reads are done before overwrite

    // Parallel prefetch of the 16 aggregate-input rows, scaled by 0.25.
    const float* base = h1 + (size_t)j * 4096;
#pragma unroll
    for (int t = 0; t < 2; ++t) {
      const int idx = (t << 9) + tid;  // 0..1023 float4 slots
      const int r = idx >> 6;
      const int c4 = (idx & 63) << 2;
      float4 f = *reinterpret_cast<const float4*>(base + r * 256 + c4);
      f.x *= 0.25f; f.y *= 0.25f; f.z *= 0.25f; f.w *= 0.25f;
      *reinterpret_cast<float4*>(&hrows[r][c4]) = f;
    }
    __syncthreads();

    float4 x = make_float4(0.f, 0.f, 0.f, 0.f);
    if (tid < 64) {
      x = *reinterpret_cast<const float4*>(&hrows[0][l4]);
#pragma unroll 1
      for (int kk = 1; kk < 16; ++kk) {
        const float4 y = *reinterpret_cast<const float4*>(&hrows[kk][l4]);
        x = mobius_step(x, y);
      }
      *reinterpret_cast<float4*>(&xs[l4]) = x;
    }
    __syncthreads();

    // mobius_matvec(x, W2): wave w accumulates d in [32w, 32w+32).
    {
      float4 p = make_float4(0.f, 0.f, 0.f, 0.f);
      const int dbase = w << 5;
      for (int d = 0; d < 32; ++d) {
        const float xd = xs[dbase + d];
        const float4 wv = *reinterpret_cast<const float4*>(
            W2 + (size_t)(dbase + d) * 256 + l4);
        p.x = fmaf(xd, wv.x, p.x);
        p.y = fmaf(xd, wv.y, p.y);
        p.z = fmaf(xd, wv.z, p.z);
        p.w = fmaf(xd, wv.w, p.w);
      }
      *reinterpret_cast<float4*>(&pp[w][l4]) = p;
    }
    __syncthreads();

    if (tid < 64) {
      float4 mx = make_float4(0.f, 0.f, 0.f, 0.f);
#pragma unroll
      for (int ww = 0; ww < 8; ++ww) {
        mx.x += pp[ww][l4 + 0];
        mx.y += pp[ww][l4 + 1];
        mx.z += pp[ww][l4 + 2];
        mx.w += pp[ww][l4 + 3];
      }
      {
        float px = wsum(dot4(x, x));
        float pm = wsum(dot4(mx, mx));
        float xn = fminf(fmaxf(sqrtf(px), EPSF), MAXNF);
        float mxn = fmaxf(sqrtf(pm), EPSF);
        float s = tanhf(mxn / xn * atanhf(xn)) / mxn;
        s *= 0.25f;  // rst * norm
        x.x = s * mx.x; x.y = s * mx.y; x.z = s * mx.z; x.w = s * mx.w;
      }
      {
        const float4 b = *reinterpret_cast<const float4*>(b2 + l4);
        x = mobius_step(x, b);
      }
      float pn = wsum(dot4(x, x));
      float yn = fminf(fmaxf(sqrtf(pn), EPSF), MAXNF);
      float s = atanhf(yn) / yn;
      float4 v;
      v.x = fmaxf(s * x.x, 0.f);
      v.y = fmaxf(s * x.y, 0.f);
      v.z = fmaxf(s * x.z, 0.f);
      v.w = fmaxf(s * x.w, 0.f);
      float pv = wsum(dot4(v, v));
      float vn = fmaxf(sqrtf(pv), EPSF);
      float s2 = tanhf(vn) / vn;
      float4 h;
      h.x = s2 * v.x; h.y = s2 * v.y; h.z = s2 * v.z; h.w = s2 * v.w;

      *reinterpret_cast<float4*>(&xs[l4]) = h;
      float m = 0.f;
      for (int d = 0; d < 256; d += 4) {
        const float4 wv =
            *reinterpret_cast<const float4*>(Wl + (size_t)lane * 256 + d);
        m = fmaf(wv.x, xs[d + 0], m);
        m = fmaf(wv.y, xs[d + 1], m);
        m = fmaf(wv.z, xs[d + 2], m);
        m = fmaf(wv.w, xs[d + 3], m);
      }
      float ph = wsum(dot4(h, h));
      float pmm = wsum(m * m);
      float hn = fminf(fmaxf(sqrtf(ph), EPSF), MAXNF);
      float mn = fmaxf(sqrtf(pmm), EPSF);
      float sc = tanhf(mn / hn * atanhf(hn)) / mn;
      float mo = sc * m;
      float bo = bl[lane];
      float pxx = wsum(mo * mo);
      float pbb = wsum(bo * bo);
      float pxb = wsum(mo * bo);
      float cx = 1.f + 2.f * pxb + pbb;
      float cy = 1.f - pxx;
      float inv = 1.f / fmaxf(1.f + 2.f * pxb + pxx * pbb, EPSF);
      out[j * 64 + lane] = (cx * mo + cy * bo) * inv;
    }
  }
}

extern "C" void kernel_launch(void* const* d_in, const int* in_sizes, int n_in,
                              void* d_out, int out_size, void* d_ws,
                              size_t ws_size, hipStream_t stream) {
  const float* features = (const float*)d_in[0];
  const float* W1 = (const float*)d_in[1];
  const float* b1 = (const float*)d_in[2];
  const float* W2 = (const float*)d_in[3];
  const float* b2 = (const float*)d_in[4];
  const float* Wl = (const float*)d_in[5];
  const float* bl = (const float*)d_in[6];
  const int* src_idx = (const int*)d_in[7];
  const int* to_fetch = (const int*)d_in[8];
  float* out = (float*)d_out;

  float* h1 = (float*)d_ws;  // 1 MB
  unsigned short* whi = (unsigned short*)((char*)d_ws + (1u << 20));   // 256 KB
  unsigned short* wlo = (unsigned short*)((char*)d_ws + (1u << 20) + (1u << 18));

  void* args[] = {(void*)&features, (void*)&W1,  (void*)&whi, (void*)&wlo,
                  (void*)&b1,       (void*)&src_idx, (void*)&to_fetch,
                  (void*)&h1,       (void*)&W2,  (void*)&b2,  (void*)&Wl,
                  (void*)&bl,       (void*)&out};
  hipLaunchCooperativeKernel((void*)fused_all, dim3(256), dim3(512), args, 0,
                             stream);
}

// Round 13
// 98.488 us; speedup vs baseline: 1.0915x; 1.0915x over previous
//
#include <hip/hip_runtime.h>
#include <math.h>

#define EPSF 1e-7f
#define MAXNF (1.0f - 1e-5f)

typedef __attribute__((ext_vector_type(8))) short short8;
typedef __attribute__((ext_vector_type(4))) float f32x4;

union Pun8 { unsigned short u[8]; short8 s; };

static __device__ __forceinline__ unsigned short f2bf_rn(float f) {
  union { float f; unsigned u; } v;
  v.f = f;
  unsigned r = v.u + 0x7fff + ((v.u >> 16) & 1);  // RNE; inputs are finite
  return (unsigned short)(r >> 16);
}
static __device__ __forceinline__ float bf2f(unsigned short h) {
  union { unsigned u; float f; } v;
  v.u = ((unsigned)h) << 16;
  return v.f;
}

// DPP-based reductions (VALU pipe).
template <int CTRL>
static __device__ __forceinline__ float dpp_add(float v) {
  int s = __builtin_amdgcn_update_dpp(0, __float_as_int(v), CTRL, 0xf, 0xf,
                                      true);
  return v + __int_as_float(s);
}
static __device__ __forceinline__ float wsum(float v) {
  v = dpp_add<0x111>(v);  // row_shr:1
  v = dpp_add<0x112>(v);  // row_shr:2
  v = dpp_add<0x114>(v);  // row_shr:4
  v = dpp_add<0x118>(v);  // row_shr:8
  v = dpp_add<0x142>(v);  // row_bcast:15
  v = dpp_add<0x143>(v);  // row_bcast:31
  return __int_as_float(__builtin_amdgcn_readlane(__float_as_int(v), 63));
}
// Per-16-lane-group sum; FULL sum valid only in lane (lane&15)==15.
static __device__ __forceinline__ float hsum16_t(float v) {
  v = dpp_add<0x111>(v);
  v = dpp_add<0x112>(v);
  v = dpp_add<0x114>(v);
  v = dpp_add<0x118>(v);
  return v;
}

__device__ __forceinline__ float dot4(const float4 a, const float4 b) {
  return a.x * b.x + a.y * b.y + a.z * b.z + a.w * b.w;
}
__device__ __forceinline__ float4 mobius_step(const float4 x, const float4 y) {
  float px = wsum(dot4(x, x));
  float py = wsum(dot4(y, y));
  float pxy = wsum(dot4(x, y));
  float cx = 1.f + 2.f * pxy + py;
  float cy = 1.f - px;
  float inv = 1.f / fmaxf(1.f + 2.f * pxy + px * py, EPSF);
  float4 r;
  r.x = (cx * x.x + cy * y.x) * inv;
  r.y = (cx * x.y + cy * y.y) * inv;
  r.z = (cx * x.z + cy * y.z) * inv;
  r.w = (cx * x.w + cy * y.w) * inv;
  return r;
}

// k0: pack W1 into bf16 hi/lo planes in MFMA B-fragment order (unchanged),
// plus zero the per-j completion counters (visible to k1 via stream order).
__global__ __launch_bounds__(256) void
k0_pack(const float* __restrict__ W1, unsigned short* __restrict__ hi,
        unsigned short* __restrict__ lo, int* __restrict__ ctr) {
  if (blockIdx.x == 0 && threadIdx.x < 64) ctr[threadIdx.x] = 0;
  const int id = blockIdx.x * 256 + threadIdx.x;  // 0..16383
  const int s = id >> 10;
  const int t = (id >> 6) & 15;
  const int l = id & 63;
  const int n = t * 16 + (l & 15);
  const int k0 = s * 32 + ((l >> 4) << 3);
  Pun8 ph, pl;
#pragma unroll
  for (int jj = 0; jj < 8; ++jj) {
    float wv = W1[(k0 + jj) * 256 + n];
    unsigned short hb = f2bf_rn(wv);
    ph.u[jj] = hb;
    pl.u[jj] = f2bf_rn(wv - bf2f(hb));
  }
  *reinterpret_cast<short8*>(hi + id * 8) = ph.s;
  *reinterpret_cast<short8*>(lo + id * 8) = pl.s;
}

// k1: 256 blocks (1/CU), 512 threads = 8 waves. Blocks 4j..4j+3 compute the
// 16 h1 rows of output j (4 pairs each, r11 structure). The LAST block to
// finish (atomicAdd(&ctr[j]) == 3) runs the layer-2 + classifier phase for j
// in-place -- no grid barrier, no spin, k2 overlapped under other GEMMs.
__global__ __launch_bounds__(512, 1) void
k1_fused(const float* __restrict__ features,
         const unsigned short* __restrict__ bhi,
         const unsigned short* __restrict__ blo, const float* __restrict__ b1,
         const int* __restrict__ src_idx, const int* __restrict__ to_fetch,
         float* __restrict__ h1, const float* __restrict__ W2,
         const float* __restrict__ b2, const float* __restrict__ Wl,
         const float* __restrict__ bl, float* __restrict__ out,
         int* __restrict__ ctr) {
  const int b4 = blockIdx.x << 2;  // first pair index of this block
  const int tid = threadIdx.x;
  const int w = tid >> 6;          // 0..7
  const int lane = tid & 63;
  const int g = lane >> 4;
  const int r16 = lane & 15;

  __shared__ __align__(16) unsigned short aH[64 * 512];  // 64 KB
  __shared__ __align__(16) unsigned short aL[64 * 512];  // 64 KB
  __shared__ float s_msp[8][64];
  __shared__ float s_fs2[64], s_srow[64];
  __shared__ int s_anode[4];
  __shared__ int s_vn[64];
  __shared__ int s_last;

  if (tid < 4) {
    const int pair = b4 + tid;
    const int jj = pair >> 4, kk = pair & 15;
    s_anode[tid] = src_idx[(to_fetch[jj] + (jj << 10)) * 16 + kk];
  }
  __syncthreads();
  if (tid < 64) s_vn[tid] = src_idx[s_anode[tid >> 4] * 16 + (tid & 15)];
  __syncthreads();

  // Stage: wave w stages rows w*8..w*8+7, two batches of 4 rows.
#pragma unroll
  for (int batch = 0; batch < 2; ++batch) {
    float4 f0[4], f1[4];
    const int rb = (w << 3) + (batch << 2);
#pragma unroll
    for (int i = 0; i < 4; ++i) {
      const float* rp = features + (size_t)s_vn[rb + i] * 512 + lane * 8;
      f0[i] = *reinterpret_cast<const float4*>(rp);
      f1[i] = *reinterpret_cast<const float4*>(rp + 4);
    }
#pragma unroll
    for (int i = 0; i < 4; ++i) {
      const int r = rb + i;
      const float fv[8] = {f0[i].x, f0[i].y, f0[i].z, f0[i].w,
                           f1[i].x, f1[i].y, f1[i].z, f1[i].w};
      Pun8 ph, pl;
      float ss = 0.f;
#pragma unroll
      for (int q = 0; q < 8; ++q) {
        ss = fmaf(fv[q], fv[q], ss);
        unsigned short hb = f2bf_rn(fv[q]);
        ph.u[q] = hb;
        pl.u[q] = f2bf_rn(fv[q] - bf2f(hb));
      }
      const int off = r * 512 + ((lane * 8) ^ ((r & 7) * 8));
      *reinterpret_cast<short8*>(&aH[off]) = ph.s;
      *reinterpret_cast<short8*>(&aL[off]) = pl.s;
      ss = wsum(ss);
      if (lane == 0) s_fs2[r] = ss;
    }
  }
  __syncthreads();

  const int g8 = g * 8;
  const int sw = (r16 & 7) * 8;
  const int tbase = w * 2;  // wave's first n-tile
  const short8* Bh = reinterpret_cast<const short8*>(bhi);
  const short8* Bl = reinterpret_cast<const short8*>(blo);

  f32x4 acc[4][2];  // [pair][ntile]
#pragma unroll
  for (int p = 0; p < 4; ++p)
#pragma unroll
    for (int i = 0; i < 2; ++i) acc[p][i] = (f32x4){0.f, 0.f, 0.f, 0.f};

  short8 A0[4][2], A1[4][2];  // [pair][hi/lo]
  short8 B0[2][2], B1[2][2];  // [ntile][hi/lo]

#define LOADA(AR, S)                                                          \
  {                                                                           \
    const int s_ = (S)&15;                                                    \
    _Pragma("unroll") for (int p_ = 0; p_ < 4; ++p_) {                        \
      const int o_ = ((p_ << 4) + r16) * 512 + (((s_ << 5) + g8) ^ sw);       \
      AR[p_][0] = *reinterpret_cast<const short8*>(&aH[o_]);                  \
      AR[p_][1] = *reinterpret_cast<const short8*>(&aL[o_]);                  \
    }                                                                         \
  }
#define LOADB(BR, S)                                                          \
  {                                                                           \
    const int s_ = (S)&15;                                                    \
    _Pragma("unroll") for (int i_ = 0; i_ < 2; ++i_) {                        \
      const int idx_ = ((s_ << 4) + tbase + i_) * 64 + lane;                  \
      BR[i_][0] = Bh[idx_];                                                   \
      BR[i_][1] = Bl[idx_];                                                   \
    }                                                                         \
  }
#define MFMAALL(AR, BR)                                                       \
  _Pragma("unroll") for (int p_ = 0; p_ < 4; ++p_)                            \
      _Pragma("unroll") for (int i_ = 0; i_ < 2; ++i_) acc[p_][i_] =          \
      __builtin_amdgcn_mfma_f32_16x16x32_bf16(AR[p_][0], BR[i_][0],           \
                                              acc[p_][i_], 0, 0, 0);          \
  _Pragma("unroll") for (int p_ = 0; p_ < 4; ++p_)                            \
      _Pragma("unroll") for (int i_ = 0; i_ < 2; ++i_) acc[p_][i_] =          \
      __builtin_amdgcn_mfma_f32_16x16x32_bf16(AR[p_][0], BR[i_][1],           \
                                              acc[p_][i_], 0, 0, 0);          \
  _Pragma("unroll") for (int p_ = 0; p_ < 4; ++p_)                            \
      _Pragma("unroll") for (int i_ = 0; i_ < 2; ++i_) acc[p_][i_] =          \
      __builtin_amdgcn_mfma_f32_16x16x32_bf16(AR[p_][1], BR[i_][0],           \
                                              acc[p_][i_], 0, 0, 0);

  LOADA(A0, 0)
  LOADB(B0, 0)
#pragma unroll 1
  for (int s = 0; s < 16; s += 2) {
    LOADB(B1, s + 1)
    LOADA(A1, s + 1)
    MFMAALL(A0, B0)
    LOADB(B0, s + 2)
    LOADA(A0, s + 2)
    MFMAALL(A1, B1)
  }

  // Row norms of mx: per-lane partial over 2 n-tiles, DPP 16-group reduce
  // (sum valid in lane r16==15), cross-wave sum in LDS.
#pragma unroll
  for (int p = 0; p < 4; ++p) {
    float rs[4];
#pragma unroll
    for (int reg = 0; reg < 4; ++reg) {
      float v = fmaf(acc[p][0][reg], acc[p][0][reg],
                     acc[p][1][reg] * acc[p][1][reg]);
      rs[reg] = hsum16_t(v);
    }
    if (r16 == 15) {
#pragma unroll
      for (int reg = 0; reg < 4; ++reg)
        s_msp[w][(p << 4) + (g << 2) + reg] = rs[reg];
    }
  }
  __syncthreads();
  if (tid < 64) {
    float ms2 = 0.f;
#pragma unroll
    for (int ww = 0; ww < 8; ++ww) ms2 += s_msp[ww][tid];
    const float xn = fminf(fmaxf(0.25f * sqrtf(s_fs2[tid]), EPSF), MAXNF);
    const float mxn = fmaxf(0.25f * sqrtf(ms2), EPSF);
    s_srow[tid] = tanhf(mxn / xn * atanhf(xn)) * 0.25f / mxn;
  }
  __syncthreads();

  // Scaled transformed rows overlay the (now dead) aH plane: 64x256 f32.
  float(*trow)[256] = reinterpret_cast<float(*)[256]>(&aH[0]);
#pragma unroll
  for (int p = 0; p < 4; ++p) {
#pragma unroll
    for (int i = 0; i < 2; ++i) {
      const int n = ((tbase + i) << 4) + r16;
#pragma unroll
      for (int reg = 0; reg < 4; ++reg) {
        const int row = (p << 4) + (g << 2) + reg;
        trow[row][n] = acc[p][i][reg] * s_srow[row];
      }
    }
  }
  __syncthreads();

  // Chained mobius_add: waves 0..3 each process one pair; store h1.
  if (w < 4) {
    const int l4 = lane << 2;
    float4 x = *reinterpret_cast<const float4*>(&trow[w * 16][l4]);
#pragma unroll 1
    for (int kk = 1; kk < 16; ++kk) {
      const float4 y = *reinterpret_cast<const float4*>(&trow[w * 16 + kk][l4]);
      x = mobius_step(x, y);
    }
    x.x *= 0.25f; x.y *= 0.25f; x.z *= 0.25f; x.w *= 0.25f;
    {
      const float4 b = *reinterpret_cast<const float4*>(b1 + l4);
      x = mobius_step(x, b);
    }
    float pn = wsum(dot4(x, x));
    float yn = fminf(fmaxf(sqrtf(pn), EPSF), MAXNF);
    float s = atanhf(yn) / yn;
    float4 v;
    v.x = fmaxf(s * x.x, 0.f);
    v.y = fmaxf(s * x.y, 0.f);
    v.z = fmaxf(s * x.z, 0.f);
    v.w = fmaxf(s * x.w, 0.f);
    float pv = wsum(dot4(v, v));
    float vn = fmaxf(sqrtf(pv), EPSF);
    float s2 = tanhf(vn) / vn;
    float4 h;
    h.x = s2 * v.x;
    h.y = s2 * v.y;
    h.z = s2 * v.z;
    h.w = s2 * v.w;
    *reinterpret_cast<float4*>(h1 + (size_t)(b4 + w) * 256 + l4) = h;
  }
#undef LOADA
#undef LOADB
#undef MFMAALL

  // ---- Last-block handoff: release our h1 rows, count arrivals for j.
  const int j = blockIdx.x >> 2;
  __threadfence();     // make this thread's h1 stores device-visible
  __syncthreads();     // all threads' stores fenced
  if (tid == 0) s_last = (atomicAdd(&ctr[j], 1) == 3) ? 1 : 0;
  __syncthreads();
  if (!s_last) return;

  // ---- k2 phase (last block of j only): layer-2 + classifier.
  __threadfence();  // acquire: h1 rows from sibling blocks are visible
  {
    const int l4 = lane << 2;
    float(*hrows)[256] = reinterpret_cast<float(*)[256]>(&aH[0]);   // 16 KB
    float* xs = reinterpret_cast<float*>(&aH[0]) + 16 * 256;        // 1 KB
    float(*pp)[256] = reinterpret_cast<float(*)[256]>(
        reinterpret_cast<float*>(&aH[0]) + 16 * 256 + 256);         // 8 KB

    // Parallel prefetch of the 16 aggregate-input rows, scaled by 0.25.
    const float* base = h1 + (size_t)j * 4096;
#pragma unroll
    for (int t = 0; t < 2; ++t) {
      const int idx = (t << 9) + tid;  // 0..1023 float4 slots
      const int r = idx >> 6;
      const int c4 = (idx & 63) << 2;
      float4 f = *reinterpret_cast<const float4*>(base + r * 256 + c4);
      f.x *= 0.25f; f.y *= 0.25f; f.z *= 0.25f; f.w *= 0.25f;
      *reinterpret_cast<float4*>(&hrows[r][c4]) = f;
    }
    __syncthreads();

    float4 x = make_float4(0.f, 0.f, 0.f, 0.f);
    if (tid < 64) {
      x = *reinterpret_cast<const float4*>(&hrows[0][l4]);
#pragma unroll 1
      for (int kk = 1; kk < 16; ++kk) {
        const float4 y = *reinterpret_cast<const float4*>(&hrows[kk][l4]);
        x = mobius_step(x, y);
      }
      *reinterpret_cast<float4*>(&xs[l4]) = x;
    }
    __syncthreads();

    // mobius_matvec(x, W2): wave w accumulates d in [32w, 32w+32).
    {
      float4 p = make_float4(0.f, 0.f, 0.f, 0.f);
      const int dbase = w << 5;
      for (int d = 0; d < 32; ++d) {
        const float xd = xs[dbase + d];
        const float4 wv = *reinterpret_cast<const float4*>(
            W2 + (size_t)(dbase + d) * 256 + l4);
        p.x = fmaf(xd, wv.x, p.x);
        p.y = fmaf(xd, wv.y, p.y);
        p.z = fmaf(xd, wv.z, p.z);
        p.w = fmaf(xd, wv.w, p.w);
      }
      *reinterpret_cast<float4*>(&pp[w][l4]) = p;
    }
    __syncthreads();

    if (tid < 64) {
      float4 mx = make_float4(0.f, 0.f, 0.f, 0.f);
#pragma unroll
      for (int ww = 0; ww < 8; ++ww) {
        mx.x += pp[ww][l4 + 0];
        mx.y += pp[ww][l4 + 1];
        mx.z += pp[ww][l4 + 2];
        mx.w += pp[ww][l4 + 3];
      }
      {
        float px = wsum(dot4(x, x));
        float pm = wsum(dot4(mx, mx));
        float xn = fminf(fmaxf(sqrtf(px), EPSF), MAXNF);
        float mxn = fmaxf(sqrtf(pm), EPSF);
        float s = tanhf(mxn / xn * atanhf(xn)) / mxn;
        s *= 0.25f;  // rst * norm
        x.x = s * mx.x; x.y = s * mx.y; x.z = s * mx.z; x.w = s * mx.w;
      }
      {
        const float4 b = *reinterpret_cast<const float4*>(b2 + l4);
        x = mobius_step(x, b);
      }
      float pn = wsum(dot4(x, x));
      float yn = fminf(fmaxf(sqrtf(pn), EPSF), MAXNF);
      float s = atanhf(yn) / yn;
      float4 v;
      v.x = fmaxf(s * x.x, 0.f);
      v.y = fmaxf(s * x.y, 0.f);
      v.z = fmaxf(s * x.z, 0.f);
      v.w = fmaxf(s * x.w, 0.f);
      float pv = wsum(dot4(v, v));
      float vn = fmaxf(sqrtf(pv), EPSF);
      float s2 = tanhf(vn) / vn;
      float4 h;
      h.x = s2 * v.x; h.y = s2 * v.y; h.z = s2 * v.z; h.w = s2 * v.w;

      *reinterpret_cast<float4*>(&xs[l4]) = h;
      float m = 0.f;
      for (int d = 0; d < 256; d += 4) {
        const float4 wv =
            *reinterpret_cast<const float4*>(Wl + (size_t)lane * 256 + d);
        m = fmaf(wv.x, xs[d + 0], m);
        m = fmaf(wv.y, xs[d + 1], m);
        m = fmaf(wv.z, xs[d + 2], m);
        m = fmaf(wv.w, xs[d + 3], m);
      }
      float ph = wsum(dot4(h, h));
      float pmm = wsum(m * m);
      float hn = fminf(fmaxf(sqrtf(ph), EPSF), MAXNF);
      float mn = fmaxf(sqrtf(pmm), EPSF);
      float sc = tanhf(mn / hn * atanhf(hn)) / mn;
      float mo = sc * m;
      float bo = bl[lane];
      float pxx = wsum(mo * mo);
      float pbb = wsum(bo * bo);
      float pxb = wsum(mo * bo);
      float cx = 1.f + 2.f * pxb + pbb;
      float cy = 1.f - pxx;
      float inv = 1.f / fmaxf(1.f + 2.f * pxb + pxx * pbb, EPSF);
      out[j * 64 + lane] = (cx * mo + cy * bo) * inv;
    }
  }
}

extern "C" void kernel_launch(void* const* d_in, const int* in_sizes, int n_in,
                              void* d_out, int out_size, void* d_ws,
                              size_t ws_size, hipStream_t stream) {
  const float* features = (const float*)d_in[0];
  const float* W1 = (const float*)d_in[1];
  const float* b1 = (const float*)d_in[2];
  const float* W2 = (const float*)d_in[3];
  const float* b2 = (const float*)d_in[4];
  const float* Wl = (const float*)d_in[5];
  const float* bl = (const float*)d_in[6];
  const int* src_idx = (const int*)d_in[7];
  const int* to_fetch = (const int*)d_in[8];
  float* out = (float*)d_out;

  float* h1 = (float*)d_ws;                                          // 1 MB
  unsigned short* whi = (unsigned short*)((char*)d_ws + (1u << 20)); // 256 KB
  unsigned short* wlo =
      (unsigned short*)((char*)d_ws + (1u << 20) + (1u << 18));      // 256 KB
  int* ctr = (int*)((char*)d_ws + (1u << 20) + (1u << 19));          // 256 B

  k0_pack<<<64, 256, 0, stream>>>(W1, whi, wlo, ctr);
  k1_fused<<<256, 512, 0, stream>>>(features, whi, wlo, b1, src_idx, to_fetch,
                                    h1, W2, b2, Wl, bl, out, ctr);
}

// Round 14
// 45.511 us; speedup vs baseline: 2.3621x; 2.1640x over previous
//
#include <hip/hip_runtime.h>
#include <math.h>

#define EPSF 1e-7f
#define MAXNF (1.0f - 1e-5f)

typedef __attribute__((ext_vector_type(8))) short short8;
typedef __attribute__((ext_vector_type(4))) float f32x4;

union Pun8 { unsigned short u[8]; short8 s; };

static __device__ __forceinline__ unsigned short f2bf_rn(float f) {
  union { float f; unsigned u; } v;
  v.f = f;
  unsigned r = v.u + 0x7fff + ((v.u >> 16) & 1);  // RNE; inputs are finite
  return (unsigned short)(r >> 16);
}
static __device__ __forceinline__ float bf2f(unsigned short h) {
  union { unsigned u; float f; } v;
  v.u = ((unsigned)h) << 16;
  return v.f;
}

// DPP-based reductions (VALU pipe).
template <int CTRL>
static __device__ __forceinline__ float dpp_add(float v) {
  int s = __builtin_amdgcn_update_dpp(0, __float_as_int(v), CTRL, 0xf, 0xf,
                                      true);
  return v + __int_as_float(s);
}
static __device__ __forceinline__ float wsum(float v) {
  v = dpp_add<0x111>(v);  // row_shr:1
  v = dpp_add<0x112>(v);  // row_shr:2
  v = dpp_add<0x114>(v);  // row_shr:4
  v = dpp_add<0x118>(v);  // row_shr:8
  v = dpp_add<0x142>(v);  // row_bcast:15
  v = dpp_add<0x143>(v);  // row_bcast:31
  return __int_as_float(__builtin_amdgcn_readlane(__float_as_int(v), 63));
}
// Per-16-lane-group sum; FULL sum valid only in lane (lane&15)==15.
static __device__ __forceinline__ float hsum16_t(float v) {
  v = dpp_add<0x111>(v);
  v = dpp_add<0x112>(v);
  v = dpp_add<0x114>(v);
  v = dpp_add<0x118>(v);
  return v;
}

__device__ __forceinline__ float dot4(const float4 a, const float4 b) {
  return a.x * b.x + a.y * b.y + a.z * b.z + a.w * b.w;
}
__device__ __forceinline__ float4 mobius_step(const float4 x, const float4 y) {
  float px = wsum(dot4(x, x));
  float py = wsum(dot4(y, y));
  float pxy = wsum(dot4(x, y));
  float cx = 1.f + 2.f * pxy + py;
  float cy = 1.f - px;
  float inv = 1.f / fmaxf(1.f + 2.f * pxy + px * py, EPSF);
  float4 r;
  r.x = (cx * x.x + cy * y.x) * inv;
  r.y = (cx * x.y + cy * y.y) * inv;
  r.z = (cx * x.z + cy * y.z) * inv;
  r.w = (cx * x.w + cy * y.w) * inv;
  return r;
}

// k0: pack W1 (512x256 f32) into bf16 hi/lo planes in MFMA B-fragment order:
// element (s,t,lane,j) = W1[s*32+(lane>>4)*8+j][t*16+(lane&15)] at short
// index ((s*16+t)*64+lane)*8 + j.
__global__ __launch_bounds__(256) void
k0_pack(const float* __restrict__ W1, unsigned short* __restrict__ hi,
        unsigned short* __restrict__ lo) {
  const int id = blockIdx.x * 256 + threadIdx.x;  // 0..16383
  const int s = id >> 10;
  const int t = (id >> 6) & 15;
  const int l = id & 63;
  const int n = t * 16 + (l & 15);
  const int k0 = s * 32 + ((l >> 4) << 3);
  Pun8 ph, pl;
#pragma unroll
  for (int jj = 0; jj < 8; ++jj) {
    float wv = W1[(k0 + jj) * 256 + n];
    unsigned short hb = f2bf_rn(wv);
    ph.u[jj] = hb;
    pl.u[jj] = f2bf_rn(wv - bf2f(hb));
  }
  *reinterpret_cast<short8*>(hi + id * 8) = ph.s;
  *reinterpret_cast<short8*>(lo + id * 8) = pl.s;
}

// k1: 256 blocks (1/CU), 512 threads = 8 waves. 4 pairs/block (r11
// structure). Changes vs r11: (a) first two B fragment sets pre-issued
// BEFORE staging (depend only on k0 output -> L2-cold latency hides under
// staging); (b) staging issues all 16 float4 loads in ONE latency window.
__global__ __launch_bounds__(512, 1) void
k1_h1(const float* __restrict__ features, const unsigned short* __restrict__ bhi,
      const unsigned short* __restrict__ blo, const float* __restrict__ b1,
      const int* __restrict__ src_idx, const int* __restrict__ to_fetch,
      float* __restrict__ h1) {
  const int b4 = blockIdx.x << 2;  // first pair index of this block
  const int tid = threadIdx.x;
  const int w = tid >> 6;          // 0..7
  const int lane = tid & 63;
  const int g = lane >> 4;
  const int r16 = lane & 15;

  __shared__ __align__(16) unsigned short aH[64 * 512];  // 64 KB
  __shared__ __align__(16) unsigned short aL[64 * 512];  // 64 KB
  __shared__ float s_msp[8][64];
  __shared__ float s_fs2[64], s_srow[64];
  __shared__ int s_anode[4];
  __shared__ int s_vn[64];

  const int g8 = g * 8;
  const int sw = (r16 & 7) * 8;
  const int tbase = w * 2;  // wave's first n-tile
  const short8* Bh = reinterpret_cast<const short8*>(bhi);
  const short8* Bl = reinterpret_cast<const short8*>(blo);

  short8 A0[4][2], A1[4][2];  // [pair][hi/lo]
  short8 B0[2][2], B1[2][2];  // [ntile][hi/lo]

#define LOADA(AR, S)                                                          \
  {                                                                           \
    const int s_ = (S)&15;                                                    \
    _Pragma("unroll") for (int p_ = 0; p_ < 4; ++p_) {                        \
      const int o_ = ((p_ << 4) + r16) * 512 + (((s_ << 5) + g8) ^ sw);       \
      AR[p_][0] = *reinterpret_cast<const short8*>(&aH[o_]);                  \
      AR[p_][1] = *reinterpret_cast<const short8*>(&aL[o_]);                  \
    }                                                                         \
  }
#define LOADB(BR, S)                                                          \
  {                                                                           \
    const int s_ = (S)&15;                                                    \
    _Pragma("unroll") for (int i_ = 0; i_ < 2; ++i_) {                        \
      const int idx_ = ((s_ << 4) + tbase + i_) * 64 + lane;                  \
      BR[i_][0] = Bh[idx_];                                                   \
      BR[i_][1] = Bl[idx_];                                                   \
    }                                                                         \
  }
#define MFMAALL(AR, BR)                                                       \
  _Pragma("unroll") for (int p_ = 0; p_ < 4; ++p_)                            \
      _Pragma("unroll") for (int i_ = 0; i_ < 2; ++i_) acc[p_][i_] =          \
      __builtin_amdgcn_mfma_f32_16x16x32_bf16(AR[p_][0], BR[i_][0],           \
                                              acc[p_][i_], 0, 0, 0);          \
  _Pragma("unroll") for (int p_ = 0; p_ < 4; ++p_)                            \
      _Pragma("unroll") for (int i_ = 0; i_ < 2; ++i_) acc[p_][i_] =          \
      __builtin_amdgcn_mfma_f32_16x16x32_bf16(AR[p_][0], BR[i_][1],           \
                                              acc[p_][i_], 0, 0, 0);          \
  _Pragma("unroll") for (int p_ = 0; p_ < 4; ++p_)                            \
      _Pragma("unroll") for (int i_ = 0; i_ < 2; ++i_) acc[p_][i_] =          \
      __builtin_amdgcn_mfma_f32_16x16x32_bf16(AR[p_][1], BR[i_][0],           \
                                              acc[p_][i_], 0, 0, 0);

  // Pre-issue B for steps 0 and 1: independent of staging (stream order
  // guarantees k0's pack is complete). Hides L2-cold B latency.
  LOADB(B0, 0)
  LOADB(B1, 1)

  if (tid < 4) {
    const int pair = b4 + tid;
    const int jj = pair >> 4, kk = pair & 15;
    s_anode[tid] = src_idx[(to_fetch[jj] + (jj << 10)) * 16 + kk];
  }
  __syncthreads();
  if (tid < 64) s_vn[tid] = src_idx[s_anode[tid >> 4] * 16 + (tid & 15)];
  __syncthreads();

  // Stage: wave w stages rows w*8..w*8+7; ALL 16 float4 loads issued in one
  // latency window, then converted/written.
  {
    float4 g0[8], g1[8];
    const int rb = w << 3;
#pragma unroll
    for (int i = 0; i < 8; ++i) {
      const float* rp = features + (size_t)s_vn[rb + i] * 512 + lane * 8;
      g0[i] = *reinterpret_cast<const float4*>(rp);
      g1[i] = *reinterpret_cast<const float4*>(rp + 4);
    }
#pragma unroll
    for (int i = 0; i < 8; ++i) {
      const int r = rb + i;
      const float fv[8] = {g0[i].x, g0[i].y, g0[i].z, g0[i].w,
                           g1[i].x, g1[i].y, g1[i].z, g1[i].w};
      Pun8 ph, pl;
      float ss = 0.f;
#pragma unroll
      for (int q = 0; q < 8; ++q) {
        ss = fmaf(fv[q], fv[q], ss);
        unsigned short hb = f2bf_rn(fv[q]);
        ph.u[q] = hb;
        pl.u[q] = f2bf_rn(fv[q] - bf2f(hb));
      }
      const int off = r * 512 + ((lane * 8) ^ ((r & 7) * 8));
      *reinterpret_cast<short8*>(&aH[off]) = ph.s;
      *reinterpret_cast<short8*>(&aL[off]) = pl.s;
      ss = wsum(ss);
      if (lane == 0) s_fs2[r] = ss;
    }
  }
  __syncthreads();

  f32x4 acc[4][2];  // [pair][ntile]
#pragma unroll
  for (int p = 0; p < 4; ++p)
#pragma unroll
    for (int i = 0; i < 2; ++i) acc[p][i] = (f32x4){0.f, 0.f, 0.f, 0.f};

  LOADA(A0, 0)
#pragma unroll 1
  for (int s = 0; s < 16; s += 2) {
    LOADA(A1, s + 1)
    MFMAALL(A0, B0)
    LOADB(B0, s + 2)
    LOADA(A0, s + 2)
    MFMAALL(A1, B1)
    LOADB(B1, s + 3)
  }

  // Row norms of mx: per-lane partial over 2 n-tiles, DPP 16-group reduce
  // (sum valid in lane r16==15), cross-wave sum in LDS.
#pragma unroll
  for (int p = 0; p < 4; ++p) {
    float rs[4];
#pragma unroll
    for (int reg = 0; reg < 4; ++reg) {
      float v = fmaf(acc[p][0][reg], acc[p][0][reg],
                     acc[p][1][reg] * acc[p][1][reg]);
      rs[reg] = hsum16_t(v);
    }
    if (r16 == 15) {
#pragma unroll
      for (int reg = 0; reg < 4; ++reg)
        s_msp[w][(p << 4) + (g << 2) + reg] = rs[reg];
    }
  }
  __syncthreads();
  if (tid < 64) {
    float ms2 = 0.f;
#pragma unroll
    for (int ww = 0; ww < 8; ++ww) ms2 += s_msp[ww][tid];
    const float xn = fminf(fmaxf(0.25f * sqrtf(s_fs2[tid]), EPSF), MAXNF);
    const float mxn = fmaxf(0.25f * sqrtf(ms2), EPSF);
    s_srow[tid] = tanhf(mxn / xn * atanhf(xn)) * 0.25f / mxn;
  }
  __syncthreads();

  // Scaled transformed rows overlay the (now dead) aH plane: 64x256 f32.
  float(*trow)[256] = reinterpret_cast<float(*)[256]>(&aH[0]);
#pragma unroll
  for (int p = 0; p < 4; ++p) {
#pragma unroll
    for (int i = 0; i < 2; ++i) {
      const int n = ((tbase + i) << 4) + r16;
#pragma unroll
      for (int reg = 0; reg < 4; ++reg) {
        const int row = (p << 4) + (g << 2) + reg;
        trow[row][n] = acc[p][i][reg] * s_srow[row];
      }
    }
  }
  __syncthreads();

  // Chained mobius_add: waves 0..3 each process one pair.
  if (w < 4) {
    const int l4 = lane << 2;
    float4 x = *reinterpret_cast<const float4*>(&trow[w * 16][l4]);
#pragma unroll 1
    for (int kk = 1; kk < 16; ++kk) {
      const float4 y = *reinterpret_cast<const float4*>(&trow[w * 16 + kk][l4]);
      x = mobius_step(x, y);
    }
    x.x *= 0.25f; x.y *= 0.25f; x.z *= 0.25f; x.w *= 0.25f;
    {
      const float4 b = *reinterpret_cast<const float4*>(b1 + l4);
      x = mobius_step(x, b);
    }
    float pn = wsum(dot4(x, x));
    float yn = fminf(fmaxf(sqrtf(pn), EPSF), MAXNF);
    float s = atanhf(yn) / yn;
    float4 v;
    v.x = fmaxf(s * x.x, 0.f);
    v.y = fmaxf(s * x.y, 0.f);
    v.z = fmaxf(s * x.z, 0.f);
    v.w = fmaxf(s * x.w, 0.f);
    float pv = wsum(dot4(v, v));
    float vn = fmaxf(sqrtf(pv), EPSF);
    float s2 = tanhf(vn) / vn;
    float4 h;
    h.x = s2 * v.x;
    h.y = s2 * v.y;
    h.z = s2 * v.z;
    h.w = s2 * v.w;
    *reinterpret_cast<float4*>(h1 + (size_t)(b4 + w) * 256 + l4) = h;
  }
#undef LOADA
#undef LOADB
#undef MFMAALL
}

// Kernel 2: 64 blocks x 256 threads (r11 version, DPP reductions).
__global__ __launch_bounds__(256) void
k2_out(const float* __restrict__ h1, const float* __restrict__ W2,
       const float* __restrict__ b2, const float* __restrict__ Wl,
       const float* __restrict__ bl, float* __restrict__ out) {
  const int j = blockIdx.x;
  const int tid = threadIdx.x;
  const int w = tid >> 6;
  const int lane = tid & 63;
  const int l4 = lane << 2;

  __shared__ float hrows[16][256];  // 16 KB
  __shared__ float xs[256];
  __shared__ float pp[4][256];      // 4 KB

  const float* base = h1 + (size_t)j * 4096;
#pragma unroll
  for (int t = 0; t < 4; ++t) {
    const int idx = (t << 8) + tid;        // 0..1023 float4 slots
    const int r = idx >> 6;
    const int c4 = (idx & 63) << 2;
    float4 f = *reinterpret_cast<const float4*>(base + r * 256 + c4);
    f.x *= 0.25f; f.y *= 0.25f; f.z *= 0.25f; f.w *= 0.25f;
    *reinterpret_cast<float4*>(&hrows[r][c4]) = f;
  }
  __syncthreads();

  float4 x = make_float4(0.f, 0.f, 0.f, 0.f);
  if (w == 0) {
    x = *reinterpret_cast<const float4*>(&hrows[0][l4]);
#pragma unroll 1
    for (int kk = 1; kk < 16; ++kk) {
      const float4 y = *reinterpret_cast<const float4*>(&hrows[kk][l4]);
      x = mobius_step(x, y);
    }
    *reinterpret_cast<float4*>(&xs[l4]) = x;
  }
  __syncthreads();

  // mobius_matvec(x, W2): wave w accumulates d in [64w, 64w+64).
  {
    float4 p = make_float4(0.f, 0.f, 0.f, 0.f);
    const int dbase = w << 6;
    for (int d = 0; d < 64; ++d) {
      const float xd = xs[dbase + d];
      const float4 wv =
          *reinterpret_cast<const float4*>(W2 + (size_t)(dbase + d) * 256 + l4);
      p.x = fmaf(xd, wv.x, p.x);
      p.y = fmaf(xd, wv.y, p.y);
      p.z = fmaf(xd, wv.z, p.z);
      p.w = fmaf(xd, wv.w, p.w);
    }
    *reinterpret_cast<float4*>(&pp[w][l4]) = p;
  }
  __syncthreads();

  if (w == 0) {
    float4 mx;
    mx.x = pp[0][l4 + 0] + pp[1][l4 + 0] + pp[2][l4 + 0] + pp[3][l4 + 0];
    mx.y = pp[0][l4 + 1] + pp[1][l4 + 1] + pp[2][l4 + 1] + pp[3][l4 + 1];
    mx.z = pp[0][l4 + 2] + pp[1][l4 + 2] + pp[2][l4 + 2] + pp[3][l4 + 2];
    mx.w = pp[0][l4 + 3] + pp[1][l4 + 3] + pp[2][l4 + 3] + pp[3][l4 + 3];
    {
      float px = wsum(dot4(x, x));
      float pm = wsum(dot4(mx, mx));
      float xn = fminf(fmaxf(sqrtf(px), EPSF), MAXNF);
      float mxn = fmaxf(sqrtf(pm), EPSF);
      float s = tanhf(mxn / xn * atanhf(xn)) / mxn;
      s *= 0.25f;  // rst * norm
      x.x = s * mx.x; x.y = s * mx.y; x.z = s * mx.z; x.w = s * mx.w;
    }
    {
      const float4 b = *reinterpret_cast<const float4*>(b2 + l4);
      x = mobius_step(x, b);
    }
    float pn = wsum(dot4(x, x));
    float yn = fminf(fmaxf(sqrtf(pn), EPSF), MAXNF);
    float s = atanhf(yn) / yn;
    float4 v;
    v.x = fmaxf(s * x.x, 0.f);
    v.y = fmaxf(s * x.y, 0.f);
    v.z = fmaxf(s * x.z, 0.f);
    v.w = fmaxf(s * x.w, 0.f);
    float pv = wsum(dot4(v, v));
    float vn = fmaxf(sqrtf(pv), EPSF);
    float s2 = tanhf(vn) / vn;
    float4 h;
    h.x = s2 * v.x; h.y = s2 * v.y; h.z = s2 * v.z; h.w = s2 * v.w;

    *reinterpret_cast<float4*>(&xs[l4]) = h;
    float m = 0.f;
    for (int d = 0; d < 256; d += 4) {
      const float4 wv =
          *reinterpret_cast<const float4*>(Wl + (size_t)lane * 256 + d);
      m = fmaf(wv.x, xs[d + 0], m);
      m = fmaf(wv.y, xs[d + 1], m);
      m = fmaf(wv.z, xs[d + 2], m);
      m = fmaf(wv.w, xs[d + 3], m);
    }
    float ph = wsum(dot4(h, h));
    float pmm = wsum(m * m);
    float hn = fminf(fmaxf(sqrtf(ph), EPSF), MAXNF);
    float mn = fmaxf(sqrtf(pmm), EPSF);
    float sc = tanhf(mn / hn * atanhf(hn)) / mn;
    float mo = sc * m;
    float bo = bl[lane];
    float pxx = wsum(mo * mo);
    float pbb = wsum(bo * bo);
    float pxb = wsum(mo * bo);
    float cx = 1.f + 2.f * pxb + pbb;
    float cy = 1.f - pxx;
    float inv = 1.f / fmaxf(1.f + 2.f * pxb + pxx * pbb, EPSF);
    out[j * 64 + lane] = (cx * mo + cy * bo) * inv;
  }
}

extern "C" void kernel_launch(void* const* d_in, const int* in_sizes, int n_in,
                              void* d_out, int out_size, void* d_ws,
                              size_t ws_size, hipStream_t stream) {
  const float* features = (const float*)d_in[0];
  const float* W1 = (const float*)d_in[1];
  const float* b1 = (const float*)d_in[2];
  const float* W2 = (const float*)d_in[3];
  const float* b2 = (const float*)d_in[4];
  const float* Wl = (const float*)d_in[5];
  const float* bl = (const float*)d_in[6];
  const int* src_idx = (const int*)d_in[7];
  const int* to_fetch = (const int*)d_in[8];
  float* out = (float*)d_out;

  float* h1 = (float*)d_ws;  // 1 MB
  unsigned short* whi = (unsigned short*)((char*)d_ws + (1u << 20));   // 256 KB
  unsigned short* wlo = (unsigned short*)((char*)d_ws + (1u << 20) + (1u << 18));

  k0_pack<<<64, 256, 0, stream>>>(W1, whi, wlo);
  k1_h1<<<256, 512, 0, stream>>>(features, whi, wlo, b1, src_idx, to_fetch, h1);
  k2_out<<<64, 256, 0, stream>>>(h1, W2, b2, Wl, bl, out);
}